// Round 2
// baseline (619.204 us; speedup 1.0000x reference)
//
#include <hip/hip_runtime.h>
#include <hip/hip_bf16.h>
#include <stdint.h>

// ---------------------------------------------------------------------------
// SelfAttention: X[4,2048,256] fp32; Wq/Wk/Wv [256,2048]; Wo [2048,256]; bo[256]
//   cast:  Xb = bf16(X); Wqt/Wkt = bf16(0.25*W^T); Wvt/Wot = bf16(W^T)
//   q = Xb @ Wqt^T ; k = Xb @ Wkt^T   [8192][2048] bf16
//   vt = Wvt @ Xb^T                    [2048][8192] bf16 (rows = h*256+d)
//   attn2: 8 waves x 32 q-rows, 32x32x16 MFMA, swapped QK^T, in-reg softmax,
//          defer-max, dbuf K/V LDS + 2-phase prefetch  -> ctx bf16 [8192][2048]
//   out = ctx @ Wot^T + bo  fp32
// ---------------------------------------------------------------------------

using short8 = __attribute__((ext_vector_type(8))) short;   // 8 bf16 = 4 VGPR
using f32x4  = __attribute__((ext_vector_type(4))) float;
using f32x16 = __attribute__((ext_vector_type(16))) float;

#define MFMA16(a, b, c) __builtin_amdgcn_mfma_f32_16x16x32_bf16((a), (b), (c), 0, 0, 0)
#define MFMA32(a, b, c) __builtin_amdgcn_mfma_f32_32x32x16_bf16((a), (b), (c), 0, 0, 0)

__device__ __forceinline__ uint16_t f2bf(float f) {
  union { float f; uint32_t u; } v; v.f = f;
  uint32_t u = v.u;
  u += 0x7fffu + ((u >> 16) & 1u);     // round-to-nearest-even
  return (uint16_t)(u >> 16);
}

__device__ __forceinline__ uint32_t cvtpk_bf16(float lo, float hi) {
  uint32_t r;
  asm("v_cvt_pk_bf16_f32 %0, %1, %2" : "=v"(r) : "v"(lo), "v"(hi));
  return r;
}

// swap a's hi-32-lane half with b's lo-32-lane half (both operands updated)
__device__ __forceinline__ void swap32(uint32_t& a, uint32_t& b) {
  asm volatile("v_permlane32_swap_b32 %0, %1" : "+v"(a), "+v"(b));
}

// global -> LDS direct (16B per lane; LDS dest = wave-uniform base + lane*16)
__device__ __forceinline__ void gll16(const void* g, void* l) {
  __builtin_amdgcn_global_load_lds(
      (const __attribute__((address_space(1))) void*)g,
      (__attribute__((address_space(3))) void*)l, 16, 0, 0);
}

// ---------------------------------------------------------------------------
__global__ __launch_bounds__(256) void cast_x_k(const float* __restrict__ X,
                                                uint16_t* __restrict__ Xb, int n4) {
  int i = blockIdx.x * 256 + threadIdx.x;
  if (i >= n4) return;
  float4 v = ((const float4*)X)[i];
  union { uint16_t u[4]; uint2 p; } r;
  r.u[0] = f2bf(v.x); r.u[1] = f2bf(v.y); r.u[2] = f2bf(v.z); r.u[3] = f2bf(v.w);
  ((uint2*)Xb)[i] = r.p;
}

// transpose-cast: W[R][C] fp32 -> Wt[C][R] bf16, times scale. grid (C/64, R/64)
__global__ __launch_bounds__(256) void tcast_k(const float* __restrict__ W,
                                               uint16_t* __restrict__ Wt,
                                               int R, int C, float scale) {
  __shared__ float T[64][65];
  int c0 = blockIdx.x * 64, r0 = blockIdx.y * 64;
  int tid = threadIdx.x;
  int cc = tid & 63;
  for (int rr = tid >> 6; rr < 64; rr += 4)
    T[rr][cc] = W[(size_t)(r0 + rr) * C + c0 + cc];
  __syncthreads();
  int n = tid >> 2, kb = (tid & 3) * 16;
  uint16_t* orow = Wt + (size_t)(c0 + n) * R + r0 + kb;
#pragma unroll
  for (int j = 0; j < 16; ++j) orow[j] = f2bf(T[kb + j][n] * scale);
}

// ---------------------------------------------------------------------------
// C[m][n] = sum_k A[m][k] * Bt[n][k]; 128x128 tile, 4 waves, BK=64.
template <int EPI>
__global__ __launch_bounds__(256) void gemm_bt_k(const uint16_t* __restrict__ A,
                                                 const uint16_t* __restrict__ Bt,
                                                 void* __restrict__ Cv,
                                                 const float* __restrict__ bias,
                                                 int M, int N, int K) {
  __shared__ uint16_t As[128 * 64];
  __shared__ uint16_t Bs[128 * 64];
  const int tid = threadIdx.x;
  const int wv = tid >> 6, lane = tid & 63;
  const int ql = lane & 15, gq = lane >> 4;
  const int wr = wv >> 1, wc = wv & 1;
  const int m0 = blockIdx.y * 128, n0 = blockIdx.x * 128;

  f32x4 acc[4][4];
#pragma unroll
  for (int i = 0; i < 4; ++i)
#pragma unroll
    for (int j = 0; j < 4; ++j) acc[i][j] = (f32x4){0.f, 0.f, 0.f, 0.f};

  const int nkb = K >> 6;
  for (int kb = 0; kb < nkb; ++kb) {
#pragma unroll
    for (int j = 0; j < 4; ++j) {
      int s = (wv * 4 + j) * 64 + lane;
      int row = s >> 3, c = s & 7;
      int gc = c ^ (row & 7);
      gll16(A + (size_t)(m0 + row) * K + kb * 64 + gc * 8, &As[(wv * 4 + j) * 512]);
      gll16(Bt + (size_t)(n0 + row) * K + kb * 64 + gc * 8, &Bs[(wv * 4 + j) * 512]);
    }
    __syncthreads();

    short8 af[4][2], bf[4][2];
#pragma unroll
    for (int mt = 0; mt < 4; ++mt)
#pragma unroll
      for (int kk = 0; kk < 2; ++kk) {
        int row = wr * 64 + mt * 16 + ql;
        int c = (kk * 4 + gq) ^ (row & 7);
        af[mt][kk] = *(const short8*)&As[row * 64 + c * 8];
      }
#pragma unroll
    for (int nt = 0; nt < 4; ++nt)
#pragma unroll
      for (int kk = 0; kk < 2; ++kk) {
        int row = wc * 64 + nt * 16 + ql;
        int c = (kk * 4 + gq) ^ (row & 7);
        bf[nt][kk] = *(const short8*)&Bs[row * 64 + c * 8];
      }
#pragma unroll
    for (int kk = 0; kk < 2; ++kk)
#pragma unroll
      for (int mt = 0; mt < 4; ++mt)
#pragma unroll
        for (int nt = 0; nt < 4; ++nt)
          acc[mt][nt] = MFMA16(af[mt][kk], bf[nt][kk], acc[mt][nt]);
    __syncthreads();
  }

#pragma unroll
  for (int mt = 0; mt < 4; ++mt)
#pragma unroll
    for (int nt = 0; nt < 4; ++nt)
#pragma unroll
      for (int r = 0; r < 4; ++r) {
        int m = m0 + wr * 64 + mt * 16 + gq * 4 + r;
        int n = n0 + wc * 64 + nt * 16 + ql;
        float v = acc[mt][nt][r];
        if (EPI == 0) {
          ((uint16_t*)Cv)[(size_t)m * N + n] = f2bf(v);
        } else {
          ((float*)Cv)[(size_t)m * N + n] = v + bias[n];
        }
      }
}

// ---------------------------------------------------------------------------
// attn2: block = 512 thr (8 waves); wave owns 32 q-rows. KVBLK=64, 32 k-tiles.
// Swapped QK: S^T[key][q] = mfma(Kfrag, Qfrag) -> lane(q=lane&31) holds 32
// scores: key = b*32 + 4*hi + (r&3) + 8*(r>>2). In-reg softmax; P packed via
// cvt_pk + permlane32_swap into PV A-frags. ctx acc: D[q(reg)][d(lane&31)].
__global__ __launch_bounds__(512, 2) void attn2_k(const uint16_t* __restrict__ qws,
                                                  const uint16_t* __restrict__ kws,
                                                  const uint16_t* __restrict__ vtws,
                                                  uint16_t* __restrict__ ctx,
                                                  int b0, int nb) {
  __shared__ uint16_t Ks[2][64 * 256];   // [key][d], chunk c at c^(key&7)
  __shared__ uint16_t Vts[2][256 * 64];  // [d][key], chunk c at c^(d&7)
  const int S = 2048;
  // XCD-grouped decode: same (h,bb) -> same blockIdx%8 (same XCD's L2)
  const int h = blockIdx.x & 7;
  const int t = blockIdx.x >> 3;
  const int bb = t >> 3, qb = t & 7;
  const int tid = threadIdx.x, w = tid >> 6, lane = tid & 63;
  const int l31 = lane & 31, hi = lane >> 5;
  const size_t SN = (size_t)nb * S;

  // ---- Q fragments (B-operand): Q[q=l31][ds*16 + hi*8 .. +7], 16 d-slots
  short8 qf[16];
  {
    const uint16_t* qrow =
        qws + (size_t)(bb * S + qb * 256 + w * 32 + l31) * 2048 + h * 256 + hi * 8;
#pragma unroll
    for (int ds = 0; ds < 16; ++ds) qf[ds] = *(const short8*)(qrow + ds * 16);
  }

  auto stage = [&](int buf, int kb) {
#pragma unroll
    for (int j = 0; j < 4; ++j) {
      int s = (j * 8 + w) * 64 + lane;
      int krow = s >> 5, kc = s & 31;
      int kgc = kc ^ (krow & 7);
      gll16(kws + (size_t)(bb * S + kb * 64 + krow) * 2048 + h * 256 + kgc * 8,
            &Ks[buf][(j * 8 + w) * 512]);
      int d = s >> 3, vc = s & 7;
      int vgc = vc ^ (d & 7);
      gll16(vtws + (size_t)(h * 256 + d) * SN + (size_t)bb * S + kb * 64 + vgc * 8,
            &Vts[buf][(j * 8 + w) * 512]);
    }
  };

  f32x16 cacc[8];
#pragma unroll
  for (int db = 0; db < 8; ++db)
#pragma unroll
    for (int r = 0; r < 16; ++r) cacc[db][r] = 0.f;
  float m_run = -3e38f, l_run = 0.f;

  stage(0, 0);
  __syncthreads();

  const int rx = (l31 & 7) << 4;          // K-tile XOR (row&7)<<4; rows l31, 32+l31
  const int hi16 = hi << 4;

  for (int kb = 0; kb < 32; ++kb) {
    const int cur = kb & 1;
    if (kb < 31) stage(cur ^ 1, kb + 1);  // prefetch: stays in flight across body

    // ---- QK: S^T = K * Q^T, two 32-key blocks
    const char* kbase = (const char*)Ks[cur];
    const char* kr0 = kbase + l31 * 512;
    const char* kr1 = kbase + (32 + l31) * 512;
    f32x16 s0, s1;
#pragma unroll
    for (int r = 0; r < 16; ++r) { s0[r] = 0.f; s1[r] = 0.f; }
    __builtin_amdgcn_s_setprio(1);
#pragma unroll
    for (int ds = 0; ds < 16; ++ds) {
      int off = (ds * 32 + hi16) ^ rx;
      short8 k0 = *(const short8*)(kr0 + off);
      short8 k1 = *(const short8*)(kr1 + off);
      s0 = MFMA32(k0, qf[ds], s0);
      s1 = MFMA32(k1, qf[ds], s1);
    }
    __builtin_amdgcn_s_setprio(0);

    // ---- in-register online softmax (lane owns q = l31; 32 of 64 keys here)
    float pm = s0[0];
#pragma unroll
    for (int r = 1; r < 16; ++r) pm = fmaxf(pm, s0[r]);
#pragma unroll
    for (int r = 0; r < 16; ++r) pm = fmaxf(pm, s1[r]);
    pm = fmaxf(pm, __shfl_xor(pm, 32));

    if (__any(pm - m_run > 8.0f)) {       // defer-max: rescale only on growth
      float mn = fmaxf(m_run, pm);
      float al = __expf(m_run - mn);
      m_run = mn;
      l_run *= al;
#pragma unroll
      for (int r = 0; r < 16; ++r) {
        float a = __shfl(al, (r & 3) + 8 * (r >> 2) + 4 * hi);
#pragma unroll
        for (int db = 0; db < 8; ++db) cacc[db][r] *= a;
      }
    }

    float ps = 0.f;
#pragma unroll
    for (int r = 0; r < 16; ++r) { s0[r] = __expf(s0[r] - m_run); ps += s0[r]; }
#pragma unroll
    for (int r = 0; r < 16; ++r) { s1[r] = __expf(s1[r] - m_run); ps += s1[r]; }
    ps += __shfl_xor(ps, 32);
    l_run += ps;

    // ---- pack P -> PV A-frags: 16 cvt_pk + 8 permlane32_swap
    uint32_t W0[4][2], W1[4][2];
#pragma unroll
    for (int g = 0; g < 4; ++g) {
      W0[g][0] = cvtpk_bf16(s0[4 * g], s0[4 * g + 1]);
      W0[g][1] = cvtpk_bf16(s0[4 * g + 2], s0[4 * g + 3]);
      W1[g][0] = cvtpk_bf16(s1[4 * g], s1[4 * g + 1]);
      W1[g][1] = cvtpk_bf16(s1[4 * g + 2], s1[4 * g + 3]);
    }
    swap32(W0[0][0], W0[1][0]); swap32(W0[0][1], W0[1][1]);
    swap32(W0[2][0], W0[3][0]); swap32(W0[2][1], W0[3][1]);
    swap32(W1[0][0], W1[1][0]); swap32(W1[0][1], W1[1][1]);
    swap32(W1[2][0], W1[3][0]); swap32(W1[2][1], W1[3][1]);
    union U { uint32_t u[4]; short8 v; };
    U pa[4];
    pa[0].u[0] = W0[0][0]; pa[0].u[1] = W0[0][1]; pa[0].u[2] = W0[1][0]; pa[0].u[3] = W0[1][1];
    pa[1].u[0] = W0[2][0]; pa[1].u[1] = W0[2][1]; pa[1].u[2] = W0[3][0]; pa[1].u[3] = W0[3][1];
    pa[2].u[0] = W1[0][0]; pa[2].u[1] = W1[0][1]; pa[2].u[2] = W1[1][0]; pa[2].u[3] = W1[1][1];
    pa[3].u[0] = W1[2][0]; pa[3].u[1] = W1[2][1]; pa[3].u[2] = W1[3][0]; pa[3].u[3] = W1[3][1];

    // ---- PV: cacc[db] += P[16 keys] * Vt ; 8 independent acc chains
    const char* vbase = (const char*)Vts[cur];
    __builtin_amdgcn_s_setprio(1);
#pragma unroll
    for (int ks = 0; ks < 4; ++ks) {
      int voff = (ks * 32 + hi16) ^ rx;   // d&7 == l31&7
#pragma unroll
      for (int db = 0; db < 8; ++db) {
        short8 vf = *(const short8*)(vbase + (db * 32 + l31) * 128 + voff);
        cacc[db] = MFMA32(pa[ks].v, vf, cacc[db]);
      }
    }
    __builtin_amdgcn_s_setprio(0);
    __syncthreads();   // drains prefetch (vmcnt) + guards buffer swap
  }

  // ---- epilogue: O[q][d] = cacc/l ; q in reg-dim -> broadcast 1/l per reg row
  float linv = 1.f / l_run;
  uint16_t* crow = ctx + (size_t)((b0 + bb) * S + qb * 256 + w * 32) * 2048 + h * 256;
#pragma unroll
  for (int r = 0; r < 16; ++r) {
    int qr = (r & 3) + 8 * (r >> 2) + 4 * hi;
    float lr = __shfl(linv, qr);
#pragma unroll
    for (int db = 0; db < 8; ++db)
      crow[(size_t)qr * 2048 + db * 32 + l31] = f2bf(cacc[db][r] * lr);
  }
}

// ---------------------------------------------------------------------------
extern "C" void kernel_launch(void* const* d_in, const int* in_sizes, int n_in,
                              void* d_out, int out_size, void* d_ws, size_t ws_size,
                              hipStream_t stream) {
  const float* X  = (const float*)d_in[0];
  const float* Wq = (const float*)d_in[1];
  const float* Wk = (const float*)d_in[2];
  const float* Wv = (const float*)d_in[3];
  const float* Wo = (const float*)d_in[4];
  const float* bo = (const float*)d_in[5];
  float* out = (float*)d_out;

  const int B = 4, S = 2048, Dm = 256, DH = 2048;
  (void)in_sizes; (void)n_in; (void)out_size;

  uint16_t* p = (uint16_t*)d_ws;
  uint16_t* Xb  = p; p += (size_t)B * S * Dm;
  uint16_t* Wqt = p; p += (size_t)DH * Dm;
  uint16_t* Wkt = p; p += (size_t)DH * Dm;
  uint16_t* Wvt = p; p += (size_t)DH * Dm;
  uint16_t* Wot = p; p += (size_t)Dm * DH;
  uint16_t* ctx = p; p += (size_t)B * S * DH;
  size_t base_elems = (size_t)(p - (uint16_t*)d_ws);
  size_t per_nb = 3ull * S * DH;
  int nb = (ws_size >= (base_elems + 4 * per_nb) * 2) ? 4 : 1;
  uint16_t* qws  = p; p += (size_t)nb * S * DH;
  uint16_t* kws  = p; p += (size_t)nb * S * DH;
  uint16_t* vtws = p;

  cast_x_k<<<dim3((B * S * Dm / 4 + 255) / 256), 256, 0, stream>>>(X, Xb, B * S * Dm / 4);
  tcast_k<<<dim3(DH / 64, Dm / 64), 256, 0, stream>>>(Wq, Wqt, Dm, DH, 0.25f);
  tcast_k<<<dim3(DH / 64, Dm / 64), 256, 0, stream>>>(Wk, Wkt, Dm, DH, 0.25f);
  tcast_k<<<dim3(DH / 64, Dm / 64), 256, 0, stream>>>(Wv, Wvt, Dm, DH, 1.0f);
  tcast_k<<<dim3(Dm / 64, DH / 64), 256, 0, stream>>>(Wo, Wot, DH, Dm, 1.0f);

  for (int c = 0; c < B / nb; ++c) {
    const uint16_t* Xc = Xb + (size_t)c * nb * S * Dm;
    int Mq = nb * S;
    gemm_bt_k<0><<<dim3(DH / 128, Mq / 128), 256, 0, stream>>>(Xc, Wqt, qws, nullptr, Mq, DH, Dm);
    gemm_bt_k<0><<<dim3(DH / 128, Mq / 128), 256, 0, stream>>>(Xc, Wkt, kws, nullptr, Mq, DH, Dm);
    gemm_bt_k<0><<<dim3(Mq / 128, DH / 128), 256, 0, stream>>>(Wvt, Xc, vtws, nullptr, DH, Mq, Dm);
    attn2_k<<<dim3(64 * nb), 512, 0, stream>>>(qws, kws, vtws, ctx, c * nb, nb);
  }
  gemm_bt_k<1><<<dim3(Dm / 128, (B * S) / 128), 256, 0, stream>>>(ctx, Wot, out, bo, B * S, Dm, DH);
}

// Round 3
// 308.801 us; speedup vs baseline: 2.0052x; 2.0052x over previous
//
#include <hip/hip_runtime.h>
#include <hip/hip_bf16.h>
#include <stdint.h>

// ---------------------------------------------------------------------------
// SelfAttention: X[4,2048,256] fp32; Wq/Wk/Wv [256,2048]; Wo [2048,256]; bo[256]
//   cast:  Xb = bf16(X); Wqt/Wkt = bf16(0.25*W^T); Wvt/Wot = bf16(W^T)
//   q = Xb @ Wqt^T ; k = Xb @ Wkt^T   [8192][2048] bf16
//   vt = Wvt @ Xb^T                    [2048][8192] bf16 (rows = h*256+d)
//   attn2: 8 waves x 32 q-rows, 32x32x16 MFMA, swapped QK^T, in-reg softmax,
//          sequential 32-key halves (fits 256 VGPR+AGPR budget, no spill),
//          defer-max, dbuf K/V LDS + prefetch  -> ctx bf16 [8192][2048]
//   out = ctx @ Wot^T + bo  fp32
// ---------------------------------------------------------------------------

using short8 = __attribute__((ext_vector_type(8))) short;   // 8 bf16 = 4 VGPR
using f32x4  = __attribute__((ext_vector_type(4))) float;
using f32x16 = __attribute__((ext_vector_type(16))) float;

#define MFMA16(a, b, c) __builtin_amdgcn_mfma_f32_16x16x32_bf16((a), (b), (c), 0, 0, 0)
#define MFMA32(a, b, c) __builtin_amdgcn_mfma_f32_32x32x16_bf16((a), (b), (c), 0, 0, 0)

__device__ __forceinline__ uint16_t f2bf(float f) {
  union { float f; uint32_t u; } v; v.f = f;
  uint32_t u = v.u;
  u += 0x7fffu + ((u >> 16) & 1u);     // round-to-nearest-even
  return (uint16_t)(u >> 16);
}

__device__ __forceinline__ uint32_t cvtpk_bf16(float lo, float hi) {
  uint32_t r;
  asm("v_cvt_pk_bf16_f32 %0, %1, %2" : "=v"(r) : "v"(lo), "v"(hi));
  return r;
}

// swap a's hi-32-lane half with b's lo-32-lane half (both operands updated)
__device__ __forceinline__ void swap32(uint32_t& a, uint32_t& b) {
  asm volatile("v_permlane32_swap_b32 %0, %1" : "+v"(a), "+v"(b));
}

// global -> LDS direct (16B per lane; LDS dest = wave-uniform base + lane*16)
__device__ __forceinline__ void gll16(const void* g, void* l) {
  __builtin_amdgcn_global_load_lds(
      (const __attribute__((address_space(1))) void*)g,
      (__attribute__((address_space(3))) void*)l, 16, 0, 0);
}

// ---------------------------------------------------------------------------
__global__ __launch_bounds__(256) void cast_x_k(const float* __restrict__ X,
                                                uint16_t* __restrict__ Xb, int n4) {
  int i = blockIdx.x * 256 + threadIdx.x;
  if (i >= n4) return;
  float4 v = ((const float4*)X)[i];
  union { uint16_t u[4]; uint2 p; } r;
  r.u[0] = f2bf(v.x); r.u[1] = f2bf(v.y); r.u[2] = f2bf(v.z); r.u[3] = f2bf(v.w);
  ((uint2*)Xb)[i] = r.p;
}

// transpose-cast: W[R][C] fp32 -> Wt[C][R] bf16, times scale. grid (C/64, R/64)
__global__ __launch_bounds__(256) void tcast_k(const float* __restrict__ W,
                                               uint16_t* __restrict__ Wt,
                                               int R, int C, float scale) {
  __shared__ float T[64][65];
  int c0 = blockIdx.x * 64, r0 = blockIdx.y * 64;
  int tid = threadIdx.x;
  int cc = tid & 63;
  for (int rr = tid >> 6; rr < 64; rr += 4)
    T[rr][cc] = W[(size_t)(r0 + rr) * C + c0 + cc];
  __syncthreads();
  int n = tid >> 2, kb = (tid & 3) * 16;
  uint16_t* orow = Wt + (size_t)(c0 + n) * R + r0 + kb;
#pragma unroll
  for (int j = 0; j < 16; ++j) orow[j] = f2bf(T[kb + j][n] * scale);
}

// ---------------------------------------------------------------------------
// C[m][n] = sum_k A[m][k] * Bt[n][k]; 128x128 tile, 4 waves, BK=64.
template <int EPI>
__global__ __launch_bounds__(256) void gemm_bt_k(const uint16_t* __restrict__ A,
                                                 const uint16_t* __restrict__ Bt,
                                                 void* __restrict__ Cv,
                                                 const float* __restrict__ bias,
                                                 int M, int N, int K) {
  __shared__ uint16_t As[128 * 64];
  __shared__ uint16_t Bs[128 * 64];
  const int tid = threadIdx.x;
  const int wv = tid >> 6, lane = tid & 63;
  const int ql = lane & 15, gq = lane >> 4;
  const int wr = wv >> 1, wc = wv & 1;
  const int m0 = blockIdx.y * 128, n0 = blockIdx.x * 128;

  f32x4 acc[4][4];
#pragma unroll
  for (int i = 0; i < 4; ++i)
#pragma unroll
    for (int j = 0; j < 4; ++j) acc[i][j] = (f32x4){0.f, 0.f, 0.f, 0.f};

  const int nkb = K >> 6;
  for (int kb = 0; kb < nkb; ++kb) {
#pragma unroll
    for (int j = 0; j < 4; ++j) {
      int s = (wv * 4 + j) * 64 + lane;
      int row = s >> 3, c = s & 7;
      int gc = c ^ (row & 7);
      gll16(A + (size_t)(m0 + row) * K + kb * 64 + gc * 8, &As[(wv * 4 + j) * 512]);
      gll16(Bt + (size_t)(n0 + row) * K + kb * 64 + gc * 8, &Bs[(wv * 4 + j) * 512]);
    }
    __syncthreads();

    short8 af[4][2], bf[4][2];
#pragma unroll
    for (int mt = 0; mt < 4; ++mt)
#pragma unroll
      for (int kk = 0; kk < 2; ++kk) {
        int row = wr * 64 + mt * 16 + ql;
        int c = (kk * 4 + gq) ^ (row & 7);
        af[mt][kk] = *(const short8*)&As[row * 64 + c * 8];
      }
#pragma unroll
    for (int nt = 0; nt < 4; ++nt)
#pragma unroll
      for (int kk = 0; kk < 2; ++kk) {
        int row = wc * 64 + nt * 16 + ql;
        int c = (kk * 4 + gq) ^ (row & 7);
        bf[nt][kk] = *(const short8*)&Bs[row * 64 + c * 8];
      }
#pragma unroll
    for (int kk = 0; kk < 2; ++kk)
#pragma unroll
      for (int mt = 0; mt < 4; ++mt)
#pragma unroll
        for (int nt = 0; nt < 4; ++nt)
          acc[mt][nt] = MFMA16(af[mt][kk], bf[nt][kk], acc[mt][nt]);
    __syncthreads();
  }

#pragma unroll
  for (int mt = 0; mt < 4; ++mt)
#pragma unroll
    for (int nt = 0; nt < 4; ++nt)
#pragma unroll
      for (int r = 0; r < 4; ++r) {
        int m = m0 + wr * 64 + mt * 16 + gq * 4 + r;
        int n = n0 + wc * 64 + nt * 16 + ql;
        float v = acc[mt][nt][r];
        if (EPI == 0) {
          ((uint16_t*)Cv)[(size_t)m * N + n] = f2bf(v);
        } else {
          ((float*)Cv)[(size_t)m * N + n] = v + bias[n];
        }
      }
}

// ---------------------------------------------------------------------------
// attn2: block = 512 thr (8 waves); wave owns 32 q-rows. KVBLK=64, 32 k-tiles.
// Swapped QK: S^T[key][q] = mfma(Kfrag, Qfrag); lane(q=l31) gets q-col.
// Each 64-key tile processed as two sequential 32-key halves so that only one
// 16-reg score block + one 8-reg P block is live at a time (no spill at the
// 256 VGPR+AGPR/wave budget of 2 waves/SIMD).
__global__ __launch_bounds__(512, 2) void attn2_k(const uint16_t* __restrict__ qws,
                                                  const uint16_t* __restrict__ kws,
                                                  const uint16_t* __restrict__ vtws,
                                                  uint16_t* __restrict__ ctx,
                                                  int b0, int nb) {
  __shared__ uint16_t Ks[2][64 * 256];   // [key][d], 16B chunk c at c^(key&7)
  __shared__ uint16_t Vts[2][256 * 64];  // [d][key], 16B chunk c at c^(d&7)
  const int S = 2048;
  // XCD-grouped decode: h == blockIdx%8 == XCD -> each XCD's L2 holds 1 head
  const int h = blockIdx.x & 7;
  const int t = blockIdx.x >> 3;
  const int bb = t >> 3, qb = t & 7;
  const int tid = threadIdx.x, w = tid >> 6, lane = tid & 63;
  const int l31 = lane & 31, hi = lane >> 5;
  const size_t SN = (size_t)nb * S;

  // ---- Q fragments (B-operand): Q[q=l31][ds*16 + hi*8 .. +7], 16 d-slots
  short8 qf[16];
  {
    const uint16_t* qrow =
        qws + (size_t)(bb * S + qb * 256 + w * 32 + l31) * 2048 + h * 256 + hi * 8;
#pragma unroll
    for (int ds = 0; ds < 16; ++ds) qf[ds] = *(const short8*)(qrow + ds * 16);
  }

  // ---- per-lane staging byte-offsets (hoisted; step per k-tile is uniform)
  uint32_t ok[4], ov[4];
#pragma unroll
  for (int j = 0; j < 4; ++j) {
    int s = (j * 8 + w) * 64 + lane;
    int krow = s >> 5, kc = s & 31;
    int kgc = kc ^ (krow & 7);
    ok[j] = (uint32_t)(((bb * S + krow) * 2048 + h * 256 + kgc * 8) * 2);
    int d = s >> 3, vc = s & 7;
    int vgc = vc ^ (d & 7);
    ov[j] = (uint32_t)((((h * 256 + d) * SN) + (size_t)bb * S + vgc * 8) * 2);
  }
  const uint32_t kstep = 64 * 2048 * 2;  // 64 key-rows
  const uint32_t vstep = 64 * 2;         // 64 key-cols

  const char* kgbase = (const char*)kws;
  const char* vgbase = (const char*)vtws;

  auto stage = [&](int buf, int kb) {
#pragma unroll
    for (int j = 0; j < 4; ++j) {
      gll16(kgbase + ok[j] + (uint32_t)kb * kstep, &Ks[buf][(j * 8 + w) * 512]);
      gll16(vgbase + ov[j] + (uint32_t)kb * vstep, &Vts[buf][(j * 8 + w) * 512]);
    }
  };

  f32x16 cacc[8];
#pragma unroll
  for (int db = 0; db < 8; ++db)
#pragma unroll
    for (int r = 0; r < 16; ++r) cacc[db][r] = 0.f;
  float m_run = -3e38f, l_run = 0.f;

  stage(0, 0);
  __syncthreads();

  const int rx = (l31 & 7) << 4;          // XOR swizzle: (row&7)<<4 bytes
  const int hi16 = hi << 4;

  // one online-softmax step over 32 keys: QK -> softmax -> pack -> PV
  auto half_step = [&](const char* krow_base, int ksbase, const char* vbase) {
    f32x16 sA, sB;
#pragma unroll
    for (int r = 0; r < 16; ++r) { sA[r] = 0.f; sB[r] = 0.f; }
    __builtin_amdgcn_s_setprio(1);
#pragma unroll
    for (int j = 0; j < 8; ++j) {        // two independent 8-MFMA chains
      int offA = ((2 * j) * 32 + hi16) ^ rx;
      int offB = ((2 * j + 1) * 32 + hi16) ^ rx;
      short8 kA = *(const short8*)(krow_base + offA);
      short8 kB = *(const short8*)(krow_base + offB);
      sA = MFMA32(kA, qf[2 * j], sA);
      sB = MFMA32(kB, qf[2 * j + 1], sB);
    }
    __builtin_amdgcn_s_setprio(0);
#pragma unroll
    for (int r = 0; r < 16; ++r) sA[r] += sB[r];

    float pm = sA[0];
#pragma unroll
    for (int r = 1; r < 16; ++r) pm = fmaxf(pm, sA[r]);
    pm = fmaxf(pm, __shfl_xor(pm, 32));

    if (__any(pm - m_run > 8.0f)) {      // defer-max: rescale only on growth
      float mn = fmaxf(m_run, pm);
      float al = __expf(m_run - mn);
      m_run = mn;
      l_run *= al;
#pragma unroll
      for (int r = 0; r < 16; ++r) {
        float a = __shfl(al, (r & 3) + 8 * (r >> 2) + 4 * hi);
#pragma unroll
        for (int db = 0; db < 8; ++db) cacc[db][r] *= a;
      }
    }

    float ps = 0.f;
#pragma unroll
    for (int r = 0; r < 16; ++r) { sA[r] = __expf(sA[r] - m_run); ps += sA[r]; }
    ps += __shfl_xor(ps, 32);
    l_run += ps;

    // pack P -> two PV A-frags: 8 cvt_pk + 4 permlane32_swap
    uint32_t W[4][2];
#pragma unroll
    for (int g = 0; g < 4; ++g) {
      W[g][0] = cvtpk_bf16(sA[4 * g], sA[4 * g + 1]);
      W[g][1] = cvtpk_bf16(sA[4 * g + 2], sA[4 * g + 3]);
    }
    swap32(W[0][0], W[1][0]); swap32(W[0][1], W[1][1]);
    swap32(W[2][0], W[3][0]); swap32(W[2][1], W[3][1]);
    union U { uint32_t u[4]; short8 v; };
    U pa0, pa1;
    pa0.u[0] = W[0][0]; pa0.u[1] = W[0][1]; pa0.u[2] = W[1][0]; pa0.u[3] = W[1][1];
    pa1.u[0] = W[2][0]; pa1.u[1] = W[2][1]; pa1.u[2] = W[3][0]; pa1.u[3] = W[3][1];

    // PV: cacc[db] += P * Vt over this half's 32 keys (8 independent chains)
    __builtin_amdgcn_s_setprio(1);
#pragma unroll
    for (int kh = 0; kh < 2; ++kh) {
      int voff = ((ksbase + kh) * 32 + hi16) ^ rx;   // d&7 == l31&7
      short8 pv = kh ? pa1.v : pa0.v;
#pragma unroll
      for (int db = 0; db < 8; ++db) {
        short8 vf = *(const short8*)(vbase + (db * 32 + l31) * 128 + voff);
        cacc[db] = MFMA32(pv, vf, cacc[db]);
      }
    }
    __builtin_amdgcn_s_setprio(0);
  };

  for (int kb = 0; kb < 32; ++kb) {
    const int cur = kb & 1;
    if (kb < 31) stage(cur ^ 1, kb + 1);  // prefetch stays in flight across body

    const char* kbase = (const char*)Ks[cur];
    const char* vbase = (const char*)Vts[cur];
    half_step(kbase + l31 * 512, 0, vbase);         // keys [0,32)
    half_step(kbase + (32 + l31) * 512, 2, vbase);  // keys [32,64)

    __syncthreads();   // drains prefetch (vmcnt) + guards buffer swap
  }

  // ---- epilogue: O[q][d] = cacc/l ; q in reg-dim -> broadcast 1/l per row
  float linv = 1.f / l_run;
  uint16_t* crow = ctx + (size_t)((b0 + bb) * S + qb * 256 + w * 32) * 2048 + h * 256;
#pragma unroll
  for (int r = 0; r < 16; ++r) {
    int qr = (r & 3) + 8 * (r >> 2) + 4 * hi;
    float lr = __shfl(linv, qr);
#pragma unroll
    for (int db = 0; db < 8; ++db)
      crow[(size_t)qr * 2048 + db * 32 + l31] = f2bf(cacc[db][r] * lr);
  }
}

// ---------------------------------------------------------------------------
extern "C" void kernel_launch(void* const* d_in, const int* in_sizes, int n_in,
                              void* d_out, int out_size, void* d_ws, size_t ws_size,
                              hipStream_t stream) {
  const float* X  = (const float*)d_in[0];
  const float* Wq = (const float*)d_in[1];
  const float* Wk = (const float*)d_in[2];
  const float* Wv = (const float*)d_in[3];
  const float* Wo = (const float*)d_in[4];
  const float* bo = (const float*)d_in[5];
  float* out = (float*)d_out;

  const int B = 4, S = 2048, Dm = 256, DH = 2048;
  (void)in_sizes; (void)n_in; (void)out_size;

  uint16_t* p = (uint16_t*)d_ws;
  uint16_t* Xb  = p; p += (size_t)B * S * Dm;
  uint16_t* Wqt = p; p += (size_t)DH * Dm;
  uint16_t* Wkt = p; p += (size_t)DH * Dm;
  uint16_t* Wvt = p; p += (size_t)DH * Dm;
  uint16_t* Wot = p; p += (size_t)Dm * DH;
  uint16_t* ctx = p; p += (size_t)B * S * DH;
  size_t base_elems = (size_t)(p - (uint16_t*)d_ws);
  size_t per_nb = 3ull * S * DH;
  int nb = (ws_size >= (base_elems + 4 * per_nb) * 2) ? 4 : 1;
  uint16_t* qws  = p; p += (size_t)nb * S * DH;
  uint16_t* kws  = p; p += (size_t)nb * S * DH;
  uint16_t* vtws = p;

  cast_x_k<<<dim3((B * S * Dm / 4 + 255) / 256), 256, 0, stream>>>(X, Xb, B * S * Dm / 4);
  tcast_k<<<dim3(DH / 64, Dm / 64), 256, 0, stream>>>(Wq, Wqt, Dm, DH, 0.25f);
  tcast_k<<<dim3(DH / 64, Dm / 64), 256, 0, stream>>>(Wk, Wkt, Dm, DH, 0.25f);
  tcast_k<<<dim3(DH / 64, Dm / 64), 256, 0, stream>>>(Wv, Wvt, Dm, DH, 1.0f);
  tcast_k<<<dim3(Dm / 64, DH / 64), 256, 0, stream>>>(Wo, Wot, DH, Dm, 1.0f);

  for (int c = 0; c < B / nb; ++c) {
    const uint16_t* Xc = Xb + (size_t)c * nb * S * Dm;
    int Mq = nb * S;
    gemm_bt_k<0><<<dim3(DH / 128, Mq / 128), 256, 0, stream>>>(Xc, Wqt, qws, nullptr, Mq, DH, Dm);
    gemm_bt_k<0><<<dim3(DH / 128, Mq / 128), 256, 0, stream>>>(Xc, Wkt, kws, nullptr, Mq, DH, Dm);
    gemm_bt_k<0><<<dim3(Mq / 128, DH / 128), 256, 0, stream>>>(Wvt, Xc, vtws, nullptr, DH, Mq, Dm);
    attn2_k<<<dim3(64 * nb), 512, 0, stream>>>(qws, kws, vtws, ctx, c * nb, nb);
  }
  gemm_bt_k<1><<<dim3(Dm / 128, (B * S) / 128), 256, 0, stream>>>(ctx, Wot, out, bo, B * S, Dm, DH);
}

// Round 4
// 274.677 us; speedup vs baseline: 2.2543x; 1.1242x over previous
//
#include <hip/hip_runtime.h>
#include <hip/hip_bf16.h>
#include <stdint.h>

// ---------------------------------------------------------------------------
// SelfAttention: X[4,2048,256] fp32; Wq/Wk/Wv [256,2048]; Wo [2048,256]; bo[256]
//   cast:  Xb = bf16(X); Wqt/Wkt = bf16(0.25*sqrt(log2e)*W^T)  [log2-domain
//   scores]; Wvt/Wot = bf16(W^T)
//   qk = Xb @ [Wqt;Wkt]^T  [8192][4096] bf16 (q cols 0..2047, k cols 2048..)
//   vt = Wvt @ Xb^T        [2048][8192] bf16 (rows = h*256+d)
//   attn2: 8 waves x 32 q-rows, 32x32x16 MFMA, swapped QK^T, in-reg softmax
//          (exp2), both-halves-QK-first pipeline for MFMA||VALU overlap,
//          defer-max, dbuf K/V LDS + prefetch  -> ctx bf16 [8192][2048]
//   out = ctx @ Wot^T + bo  fp32
// ---------------------------------------------------------------------------

using short8 = __attribute__((ext_vector_type(8))) short;   // 8 bf16 = 4 VGPR
using f32x4  = __attribute__((ext_vector_type(4))) float;
using f32x16 = __attribute__((ext_vector_type(16))) float;

#define MFMA16(a, b, c) __builtin_amdgcn_mfma_f32_16x16x32_bf16((a), (b), (c), 0, 0, 0)
#define MFMA32(a, b, c) __builtin_amdgcn_mfma_f32_32x32x16_bf16((a), (b), (c), 0, 0, 0)

#if __has_builtin(__builtin_amdgcn_exp2f)
#define EXP2(x) __builtin_amdgcn_exp2f(x)
#else
#define EXP2(x) exp2f(x)
#endif

__device__ __forceinline__ uint16_t f2bf(float f) {
  union { float f; uint32_t u; } v; v.f = f;
  uint32_t u = v.u;
  u += 0x7fffu + ((u >> 16) & 1u);     // round-to-nearest-even
  return (uint16_t)(u >> 16);
}

__device__ __forceinline__ uint32_t cvtpk_bf16(float lo, float hi) {
  uint32_t r;
  asm("v_cvt_pk_bf16_f32 %0, %1, %2" : "=v"(r) : "v"(lo), "v"(hi));
  return r;
}

// swap a's hi-32-lane half with b's lo-32-lane half (both operands updated)
__device__ __forceinline__ void swap32(uint32_t& a, uint32_t& b) {
  asm volatile("v_permlane32_swap_b32 %0, %1" : "+v"(a), "+v"(b));
}

// global -> LDS direct (16B per lane; LDS dest = wave-uniform base + lane*16)
__device__ __forceinline__ void gll16(const void* g, void* l) {
  __builtin_amdgcn_global_load_lds(
      (const __attribute__((address_space(1))) void*)g,
      (__attribute__((address_space(3))) void*)l, 16, 0, 0);
}

// ---------------------------------------------------------------------------
__global__ __launch_bounds__(256) void cast_x_k(const float* __restrict__ X,
                                                uint16_t* __restrict__ Xb, int n4) {
  int i = blockIdx.x * 256 + threadIdx.x;
  if (i >= n4) return;
  float4 v = ((const float4*)X)[i];
  union { uint16_t u[4]; uint2 p; } r;
  r.u[0] = f2bf(v.x); r.u[1] = f2bf(v.y); r.u[2] = f2bf(v.z); r.u[3] = f2bf(v.w);
  ((uint2*)Xb)[i] = r.p;
}

// transpose-cast: W[R][C] fp32 -> Wt[C][R] bf16, times scale. grid (C/64, R/64)
__global__ __launch_bounds__(256) void tcast_k(const float* __restrict__ W,
                                               uint16_t* __restrict__ Wt,
                                               int R, int C, float scale) {
  __shared__ float T[64][65];
  int c0 = blockIdx.x * 64, r0 = blockIdx.y * 64;
  int tid = threadIdx.x;
  int cc = tid & 63;
  for (int rr = tid >> 6; rr < 64; rr += 4)
    T[rr][cc] = W[(size_t)(r0 + rr) * C + c0 + cc];
  __syncthreads();
  int n = tid >> 2, kb = (tid & 3) * 16;
  uint16_t* orow = Wt + (size_t)(c0 + n) * R + r0 + kb;
#pragma unroll
  for (int j = 0; j < 16; ++j) orow[j] = f2bf(T[kb + j][n] * scale);
}

// ---------------------------------------------------------------------------
// C[m][n] = sum_k A[m][k] * Bt[n][k]; 128x128 tile, 4 waves, BK=64.
template <int EPI>
__global__ __launch_bounds__(256) void gemm_bt_k(const uint16_t* __restrict__ A,
                                                 const uint16_t* __restrict__ Bt,
                                                 void* __restrict__ Cv,
                                                 const float* __restrict__ bias,
                                                 int M, int N, int K) {
  __shared__ uint16_t As[128 * 64];
  __shared__ uint16_t Bs[128 * 64];
  const int tid = threadIdx.x;
  const int wv = tid >> 6, lane = tid & 63;
  const int ql = lane & 15, gq = lane >> 4;
  const int wr = wv >> 1, wc = wv & 1;
  const int m0 = blockIdx.y * 128, n0 = blockIdx.x * 128;

  f32x4 acc[4][4];
#pragma unroll
  for (int i = 0; i < 4; ++i)
#pragma unroll
    for (int j = 0; j < 4; ++j) acc[i][j] = (f32x4){0.f, 0.f, 0.f, 0.f};

  const int nkb = K >> 6;
  for (int kb = 0; kb < nkb; ++kb) {
#pragma unroll
    for (int j = 0; j < 4; ++j) {
      int s = (wv * 4 + j) * 64 + lane;
      int row = s >> 3, c = s & 7;
      int gc = c ^ (row & 7);
      gll16(A + (size_t)(m0 + row) * K + kb * 64 + gc * 8, &As[(wv * 4 + j) * 512]);
      gll16(Bt + (size_t)(n0 + row) * K + kb * 64 + gc * 8, &Bs[(wv * 4 + j) * 512]);
    }
    __syncthreads();

    short8 af[4][2], bf[4][2];
#pragma unroll
    for (int mt = 0; mt < 4; ++mt)
#pragma unroll
      for (int kk = 0; kk < 2; ++kk) {
        int row = wr * 64 + mt * 16 + ql;
        int c = (kk * 4 + gq) ^ (row & 7);
        af[mt][kk] = *(const short8*)&As[row * 64 + c * 8];
      }
#pragma unroll
    for (int nt = 0; nt < 4; ++nt)
#pragma unroll
      for (int kk = 0; kk < 2; ++kk) {
        int row = wc * 64 + nt * 16 + ql;
        int c = (kk * 4 + gq) ^ (row & 7);
        bf[nt][kk] = *(const short8*)&Bs[row * 64 + c * 8];
      }
#pragma unroll
    for (int kk = 0; kk < 2; ++kk)
#pragma unroll
      for (int mt = 0; mt < 4; ++mt)
#pragma unroll
        for (int nt = 0; nt < 4; ++nt)
          acc[mt][nt] = MFMA16(af[mt][kk], bf[nt][kk], acc[mt][nt]);
    __syncthreads();
  }

#pragma unroll
  for (int mt = 0; mt < 4; ++mt)
#pragma unroll
    for (int nt = 0; nt < 4; ++nt)
#pragma unroll
      for (int r = 0; r < 4; ++r) {
        int m = m0 + wr * 64 + mt * 16 + gq * 4 + r;
        int n = n0 + wc * 64 + nt * 16 + ql;
        float v = acc[mt][nt][r];
        if (EPI == 0) {
          ((uint16_t*)Cv)[(size_t)m * N + n] = f2bf(v);
        } else {
          ((float*)Cv)[(size_t)m * N + n] = v + bias[n];
        }
      }
}

// ---------------------------------------------------------------------------
// attn2: block = 512 thr (8 waves); wave owns 32 q-rows. KVBLK=64, 32 k-tiles.
// Swapped QK: S^T[key][q] = mfma(Kfrag, Qfrag); lane(q=l31) gets q-col.
// Both 32-key halves' QK chains issue first (interleaved); softmax/pack of
// half h overlaps in-flight MFMAs of the other half / PV.  Scores arrive in
// log2 domain (sqrt(log2e) folded into Wq,Wk) -> exp2 directly.
__global__ __launch_bounds__(512, 2) void attn2_k(const uint16_t* __restrict__ qk,
                                                  const uint16_t* __restrict__ vtws,
                                                  uint16_t* __restrict__ ctx,
                                                  int b0, int nb) {
  __shared__ uint16_t Ks[2][64 * 256];   // [key][d], 16B chunk c at c^(key&7)
  __shared__ uint16_t Vts[2][256 * 64];  // [d][key], 16B chunk c at c^(d&7)
  const int S = 2048;
  // XCD-grouped decode: h == blockIdx%8 == XCD -> each XCD's L2 holds 1 head
  const int h = blockIdx.x & 7;
  const int t = blockIdx.x >> 3;
  const int bb = t >> 3, qb = t & 7;
  const int tid = threadIdx.x, w = tid >> 6, lane = tid & 63;
  const int l31 = lane & 31, hi = lane >> 5;
  const size_t SN = (size_t)nb * S;

  // ---- Q fragments (B-operand): Q[q=l31][ds*16 + hi*8 .. +7], 16 d-slots
  short8 qf[16];
  {
    const uint16_t* qrow =
        qk + (size_t)(bb * S + qb * 256 + w * 32 + l31) * 4096 + h * 256 + hi * 8;
#pragma unroll
    for (int ds = 0; ds < 16; ++ds) qf[ds] = *(const short8*)(qrow + ds * 16);
  }

  // ---- per-lane staging byte-offsets (hoisted; step per k-tile is uniform)
  uint32_t ok[4], ov[4];
#pragma unroll
  for (int j = 0; j < 4; ++j) {
    int s = (j * 8 + w) * 64 + lane;
    int krow = s >> 5, kc = s & 31;
    int kgc = kc ^ (krow & 7);
    ok[j] = (uint32_t)(((bb * S + krow) * 4096 + 2048 + h * 256 + kgc * 8) * 2);
    int d = s >> 3, vc = s & 7;
    int vgc = vc ^ (d & 7);
    ov[j] = (uint32_t)((((h * 256 + d) * SN) + (size_t)bb * S + vgc * 8) * 2);
  }
  const uint32_t kstep = 64 * 4096 * 2;  // 64 key-rows (qk row stride 4096)
  const uint32_t vstep = 64 * 2;         // 64 key-cols

  const char* kgbase = (const char*)qk;
  const char* vgbase = (const char*)vtws;

  auto stage = [&](int buf, int kb) {
#pragma unroll
    for (int j = 0; j < 4; ++j) {
      gll16(kgbase + ok[j] + (uint32_t)kb * kstep, &Ks[buf][(j * 8 + w) * 512]);
      gll16(vgbase + ov[j] + (uint32_t)kb * vstep, &Vts[buf][(j * 8 + w) * 512]);
    }
  };

  f32x16 cacc[8];
#pragma unroll
  for (int db = 0; db < 8; ++db)
#pragma unroll
    for (int r = 0; r < 16; ++r) cacc[db][r] = 0.f;
  float m_run = -3e38f, l_run = 0.f;

  stage(0, 0);
  __syncthreads();

  const int rx = (l31 & 7) << 4;          // XOR swizzle: (row&7)<<4 bytes
  const int hi16 = hi << 4;

  // softmax (log2 domain) + pack + PV over one 32-key half held in s
  auto sm_pv = [&](f32x16& s, int ksbase, const char* vbase) {
    float pm = fmaxf(
        fmaxf(fmaxf(fmaxf(s[0], s[1]), fmaxf(s[2], s[3])),
              fmaxf(fmaxf(s[4], s[5]), fmaxf(s[6], s[7]))),
        fmaxf(fmaxf(fmaxf(s[8], s[9]), fmaxf(s[10], s[11])),
              fmaxf(fmaxf(s[12], s[13]), fmaxf(s[14], s[15]))));
    pm = fmaxf(pm, __shfl_xor(pm, 32));

    if (__any(pm - m_run > 8.0f)) {      // defer-max: rescale only on growth
      float mn = fmaxf(m_run, pm);
      float al = EXP2(m_run - mn);
      m_run = mn;
      l_run *= al;
#pragma unroll
      for (int r = 0; r < 16; ++r) {
        float a = __shfl(al, (r & 3) + 8 * (r >> 2) + 4 * hi);
#pragma unroll
        for (int db = 0; db < 8; ++db) cacc[db][r] *= a;
      }
    }

    float ps = 0.f;
#pragma unroll
    for (int r = 0; r < 16; ++r) { s[r] = EXP2(s[r] - m_run); ps += s[r]; }
    ps += __shfl_xor(ps, 32);
    l_run += ps;

    // pack P -> two PV A-frags: 8 cvt_pk + 4 permlane32_swap
    uint32_t W[4][2];
#pragma unroll
    for (int g = 0; g < 4; ++g) {
      W[g][0] = cvtpk_bf16(s[4 * g], s[4 * g + 1]);
      W[g][1] = cvtpk_bf16(s[4 * g + 2], s[4 * g + 3]);
    }
    swap32(W[0][0], W[1][0]); swap32(W[0][1], W[1][1]);
    swap32(W[2][0], W[3][0]); swap32(W[2][1], W[3][1]);
    union U { uint32_t u[4]; short8 v; };
    U pa0, pa1;
    pa0.u[0] = W[0][0]; pa0.u[1] = W[0][1]; pa0.u[2] = W[1][0]; pa0.u[3] = W[1][1];
    pa1.u[0] = W[2][0]; pa1.u[1] = W[2][1]; pa1.u[2] = W[3][0]; pa1.u[3] = W[3][1];

    // PV: cacc[db] += P * Vt over this half's 32 keys (8 independent chains)
    __builtin_amdgcn_s_setprio(1);
#pragma unroll
    for (int kh = 0; kh < 2; ++kh) {
      int voff = ((ksbase + kh) * 32 + hi16) ^ rx;   // d&7 == l31&7
      short8 pv = kh ? pa1.v : pa0.v;
#pragma unroll
      for (int db = 0; db < 8; ++db) {
        short8 vf = *(const short8*)(vbase + (db * 32 + l31) * 128 + voff);
        cacc[db] = MFMA32(pv, vf, cacc[db]);
      }
    }
    __builtin_amdgcn_s_setprio(0);
  };

  for (int kb = 0; kb < 32; ++kb) {
    const int cur = kb & 1;
    if (kb < 31) stage(cur ^ 1, kb + 1);  // prefetch stays in flight across body

    const char* kbase = (const char*)Ks[cur];
    const char* vbase = (const char*)Vts[cur];
    const char* kr0 = kbase + l31 * 512;
    const char* kr1 = kbase + (32 + l31) * 512;

    // ---- QK for BOTH halves first (2 interleaved chains); the following
    // softmax VALU then overlaps the tail of these MFMAs / PV MFMAs.
    f32x16 sA, sB;
#pragma unroll
    for (int r = 0; r < 16; ++r) { sA[r] = 0.f; sB[r] = 0.f; }
    __builtin_amdgcn_s_setprio(1);
#pragma unroll
    for (int ds = 0; ds < 16; ++ds) {
      int off = (ds * 32 + hi16) ^ rx;
      short8 kA = *(const short8*)(kr0 + off);
      short8 kB = *(const short8*)(kr1 + off);
      sA = MFMA32(kA, qf[ds], sA);
      sB = MFMA32(kB, qf[ds], sB);
    }
    __builtin_amdgcn_s_setprio(0);

    sm_pv(sA, 0, vbase);   // keys [0,32)
    sm_pv(sB, 2, vbase);   // keys [32,64)

    __syncthreads();   // drains prefetch (vmcnt) + guards buffer swap
  }

  // ---- epilogue: O[q][d] = cacc/l ; q in reg-dim -> broadcast 1/l per row
  float linv = 1.f / l_run;
  uint16_t* crow = ctx + (size_t)((b0 + bb) * S + qb * 256 + w * 32) * 2048 + h * 256;
#pragma unroll
  for (int r = 0; r < 16; ++r) {
    int qr = (r & 3) + 8 * (r >> 2) + 4 * hi;
    float lr = __shfl(linv, qr);
#pragma unroll
    for (int db = 0; db < 8; ++db)
      crow[(size_t)qr * 2048 + db * 32 + l31] = f2bf(cacc[db][r] * lr);
  }
}

// ---------------------------------------------------------------------------
extern "C" void kernel_launch(void* const* d_in, const int* in_sizes, int n_in,
                              void* d_out, int out_size, void* d_ws, size_t ws_size,
                              hipStream_t stream) {
  const float* X  = (const float*)d_in[0];
  const float* Wq = (const float*)d_in[1];
  const float* Wk = (const float*)d_in[2];
  const float* Wv = (const float*)d_in[3];
  const float* Wo = (const float*)d_in[4];
  const float* bo = (const float*)d_in[5];
  float* out = (float*)d_out;

  const int B = 4, S = 2048, Dm = 256, DH = 2048;
  (void)in_sizes; (void)n_in; (void)out_size; (void)ws_size;

  uint16_t* p = (uint16_t*)d_ws;
  uint16_t* Xb  = p; p += (size_t)B * S * Dm;
  uint16_t* Wqt = p; p += (size_t)DH * Dm;   // Wqt,Wkt contiguous => fused B
  uint16_t* Wkt = p; p += (size_t)DH * Dm;
  uint16_t* Wvt = p; p += (size_t)DH * Dm;
  uint16_t* Wot = p; p += (size_t)Dm * DH;
  uint16_t* ctx = p; p += (size_t)B * S * DH;
  uint16_t* qkw = p; p += (size_t)B * S * (2 * DH);  // [8192][4096]
  uint16_t* vtws = p;                                // [2048][8192]

  // sqrt(log2e) folded into q,k scales -> scores in log2 domain
  const float qs = 0.25f * 1.2011224087864498f;

  cast_x_k<<<dim3((B * S * Dm / 4 + 255) / 256), 256, 0, stream>>>(X, Xb, B * S * Dm / 4);
  tcast_k<<<dim3(DH / 64, Dm / 64), 256, 0, stream>>>(Wq, Wqt, Dm, DH, qs);
  tcast_k<<<dim3(DH / 64, Dm / 64), 256, 0, stream>>>(Wk, Wkt, Dm, DH, qs);
  tcast_k<<<dim3(DH / 64, Dm / 64), 256, 0, stream>>>(Wv, Wvt, Dm, DH, 1.0f);
  tcast_k<<<dim3(Dm / 64, DH / 64), 256, 0, stream>>>(Wo, Wot, DH, Dm, 1.0f);

  // fused q|k projection: [8192][4096]
  gemm_bt_k<0><<<dim3((2 * DH) / 128, (B * S) / 128), 256, 0, stream>>>(
      Xb, Wqt, qkw, nullptr, B * S, 2 * DH, Dm);
  // vt = Wvt @ Xb^T : [2048][8192]
  gemm_bt_k<0><<<dim3((B * S) / 128, DH / 128), 256, 0, stream>>>(
      Wvt, Xb, vtws, nullptr, DH, B * S, Dm);
  attn2_k<<<dim3(64 * B), 512, 0, stream>>>(qkw, vtws, ctx, 0, B);
  gemm_bt_k<1><<<dim3(Dm / 128, (B * S) / 128), 256, 0, stream>>>(
      ctx, Wot, out, bo, B * S, Dm, DH);
}